// Round 13
// baseline (147.664 us; speedup 1.0000x reference)
//
#include <hip/hip_runtime.h>
#include <hip/hip_bf16.h>
#include <stdint.h>

// ---------------------------------------------------------------------------
// MaskedPolicy: obs->MLP->heads (masked log-softmax, gather, entropy) + critic
// B=8192 OBS=512 HID=1024 N*SUM=2560 (+512 critic cols = 3072 fused GEMM3)
// v12: R11's seg-major coalesced mask/act layouts + hardware-true LDS DMA
// dests (global_load_lds writes lane i at uniform_base + i*size — rule #21).
// ---------------------------------------------------------------------------

typedef __bf16 v8bf __attribute__((ext_vector_type(8)));
typedef float  v4f  __attribute__((ext_vector_type(4)));

__device__ __forceinline__ void load_lds16(const void* g, void* l) {
  auto gp = (const __attribute__((address_space(1))) char*)(uintptr_t)g;
  auto lp = (__attribute__((address_space(3))) char*)(uintptr_t)l;
  __builtin_amdgcn_global_load_lds(gp, lp, 16, 0, 0);
}
__device__ __forceinline__ void load_lds4(const void* g, void* l) {
  auto gp = (const __attribute__((address_space(1))) char*)(uintptr_t)g;
  auto lp = (__attribute__((address_space(3))) char*)(uintptr_t)l;
  __builtin_amdgcn_global_load_lds(gp, lp, 4, 0, 0);
}

#define BARRIER __builtin_amdgcn_s_barrier()
#define SCHEDB  __builtin_amdgcn_sched_barrier(0)
#define WAIT_LGKM0 do { asm volatile("s_waitcnt lgkmcnt(0)" ::: "memory"); SCHEDB; } while (0)
#define WAIT_LGKM8 do { asm volatile("s_waitcnt lgkmcnt(8)" ::: "memory"); SCHEDB; } while (0)
#define WAIT_VM8   do { asm volatile("s_waitcnt vmcnt(8)" ::: "memory"); SCHEDB; } while (0)
#define WAIT_VM0   do { asm volatile("s_waitcnt vmcnt(0)" ::: "memory"); SCHEDB; } while (0)

// ---------------------------------------------------------------------------
// prep mega-kernel: weight transposes + obs conversion + bias concat
// + seg-major mask packing (84MB -> 2.6MB) + seg-major action transpose.
// block ranges: [0,4608) transposes | [4608,6656) obs | [6656,6668) bias |
// [6668,7948) mask pack + act transpose (thread g -> seg=g/8192, row=g%8192)
// ---------------------------------------------------------------------------

__global__ __launch_bounds__(256)
void prep_kernel(const float* __restrict__ obs,
                 const float* __restrict__ W1, const float* __restrict__ W2,
                 const float* __restrict__ headsW, const float* __restrict__ Wc1,
                 const float* __restrict__ headsb, const float* __restrict__ bc1,
                 const int* __restrict__ masks, const int* __restrict__ actions,
                 int4* __restrict__ obsB,
                 __hip_bfloat16* __restrict__ W1t, __hip_bfloat16* __restrict__ W2t,
                 __hip_bfloat16* __restrict__ Wbigt, float* __restrict__ biasc,
                 uint32_t* __restrict__ packedT, int* __restrict__ actT) {
  const int b = blockIdx.x;
  const int tid = threadIdx.x;
  if (b < 4608) {
    const float* in; __hip_bfloat16* outp; int R, C, bxx, byy;
    if (b < 512)       { in = W1;  outp = W1t; R = 512;  C = 1024; bxx = b % 32; byy = b / 32; }
    else if (b < 1536) { int i = b - 512;  in = W2;  outp = W2t; R = 1024; C = 1024; bxx = i % 32; byy = i / 32; }
    else if (b < 4096) { int i = b - 1536; int bz = i / 320; i %= 320;
                         in = headsW + (size_t)bz * 1024 * 320;
                         outp = Wbigt + (size_t)bz * 320 * 1024;
                         R = 1024; C = 320; bxx = i % 10; byy = i / 10; }
    else               { int i = b - 4096; in = Wc1; outp = Wbigt + 2560 * 1024;
                         R = 1024; C = 512; bxx = i % 16; byy = i / 16; }
    __shared__ float t[32][33];
    const int x = tid & 31, y = tid >> 5;
    const int bx0 = bxx * 32, by0 = byy * 32;
#pragma unroll
    for (int i = 0; i < 32; i += 8)
      t[y + i][x] = in[(size_t)(by0 + y + i) * C + bx0 + x];
    __syncthreads();
#pragma unroll
    for (int i = 0; i < 32; i += 8)
      outp[(size_t)(bx0 + y + i) * R + by0 + x] = __float2bfloat16(t[x][y + i]);
  } else if (b < 6656) {
    const int i = (b - 4608) * 256 + tid;   // < 524288
    const float4 x = ((const float4*)obs)[i * 2], y = ((const float4*)obs)[i * 2 + 1];
    union { __hip_bfloat16 h[8]; int4 v; } u;
    u.h[0] = __float2bfloat16(x.x); u.h[1] = __float2bfloat16(x.y);
    u.h[2] = __float2bfloat16(x.z); u.h[3] = __float2bfloat16(x.w);
    u.h[4] = __float2bfloat16(y.x); u.h[5] = __float2bfloat16(y.y);
    u.h[6] = __float2bfloat16(y.z); u.h[7] = __float2bfloat16(y.w);
    obsB[i] = u.v;
  } else if (b < 6668) {
    const int i = (b - 6656) * 256 + tid;
    if (i < 2560) biasc[i] = headsb[i];
    else if (i < 3072) biasc[i] = bc1[i - 2560];
  } else {
    // seg-major pack: thread g -> (seg,row); writes coalesced (stride 8B/4B)
    const int g = (b - 6668) * 256 + tid;   // < 327680
    const int seg = g >> 13, row = g & 8191;
    const int4* mp = (const int4*)(masks + (size_t)row * 2560 + seg * 64);
    uint32_t lo = 0, hi = 0;
#pragma unroll
    for (int j = 0; j < 8; ++j) {
      const int4 a = mp[j];
      lo |= (a.x ? 1u : 0u) << (4 * j);
      lo |= (a.y ? 1u : 0u) << (4 * j + 1);
      lo |= (a.z ? 1u : 0u) << (4 * j + 2);
      lo |= (a.w ? 1u : 0u) << (4 * j + 3);
    }
#pragma unroll
    for (int j = 0; j < 8; ++j) {
      const int4 a = mp[8 + j];
      hi |= (a.x ? 1u : 0u) << (4 * j);
      hi |= (a.y ? 1u : 0u) << (4 * j + 1);
      hi |= (a.z ? 1u : 0u) << (4 * j + 2);
      hi |= (a.w ? 1u : 0u) << (4 * j + 3);
    }
    packedT[(size_t)g * 2]     = lo;
    packedT[(size_t)g * 2 + 1] = hi;
    actT[g] = actions[row * 40 + seg];
  }
}

// ---------------------------------------------------------------------------
// shared swizzle helpers (verified: pass + 0 bank conflicts)
// ---------------------------------------------------------------------------

__device__ __forceinline__ void decode_chunk(int o, int& r, int& cb) {
  const int L = o ^ (((o >> 9) & 1) << 5);
  r  = ((L >> 10) << 4) | ((L >> 6) & 15);
  cb = ((L >> 4) & 3) << 4;
}

// ---------------------------------------------------------------------------
// G1/G2 GEMM: 128x128, BK=64, 4 waves, dbuf, 2 blocks/CU (round-4, verified)
// ---------------------------------------------------------------------------

__global__ __launch_bounds__(256, 2)
void gemm_db(const __hip_bfloat16* __restrict__ A,
             const __hip_bfloat16* __restrict__ Bt,
             const float* __restrict__ bias,
             __hip_bfloat16* __restrict__ C,
             int N, int K, int relu_from, int gx) {
  __shared__ char smem[65536];

  const int tid  = threadIdx.x;
  const int lane = tid & 63;
  const int wave = tid >> 6;
  const int wr = wave >> 1, wc = wave & 1;
  const int lr = lane & 15, ls = lane >> 4;

  const int nwg = gridDim.x;
  const int q8 = nwg >> 3;
  const int id = (blockIdx.x & 7) * q8 + (blockIdx.x >> 3);
  const int bx = id % gx, by = id / gx;
  const int m0 = by * 128, n0 = bx * 128;

  int r0, c0, r1, c1;
  decode_chunk(tid * 16, r0, c0);
  decode_chunk(tid * 16 + 4096, r1, c1);

  const size_t K2 = (size_t)K * 2;
  const char* pA0 = (const char*)A  + (size_t)(m0 + r0) * K2 + c0;
  const char* pA1 = (const char*)A  + (size_t)(m0 + r1) * K2 + c1;
  const char* pB0 = (const char*)Bt + (size_t)(n0 + r0) * K2 + c0;
  const char* pB1 = (const char*)Bt + (size_t)(n0 + r1) * K2 + c1;

  char* const s0 = smem + (tid << 4);

  auto stage = [&](int buf) {
    char* d = s0 + (buf << 15);
    load_lds16(pA0,      d);
    load_lds16(pA1,      d + 4096);
    load_lds16(pA0 + 64, d + 8192);
    load_lds16(pA1 + 64, d + 12288);
    load_lds16(pB0,      d + 16384);
    load_lds16(pB1,      d + 20480);
    load_lds16(pB0 + 64, d + 24576);
    load_lds16(pB1 + 64, d + 28672);
    pA0 += 128; pA1 += 128; pB0 += 128; pB1 += 128;
  };

  const int laneOff = lr * 64 + ((ls * 16) ^ ((lr & 8) << 2));

  v4f acc[4][4] = {};

  auto tile = [&](int buf, bool doStage, auto gate) {
    const char* aB = smem + (buf << 15) + wr * 4096 + laneOff;
    const char* bB = smem + (buf << 15) + 16384 + wc * 4096 + laneOff;
    v8bf a0[4], b0[4], a1[4], b1[4];
#pragma unroll
    for (int m = 0; m < 4; ++m) a0[m] = *(const v8bf*)(aB + m * 1024);
#pragma unroll
    for (int n = 0; n < 4; ++n) b0[n] = *(const v8bf*)(bB + n * 1024);
#pragma unroll
    for (int m = 0; m < 4; ++m) a1[m] = *(const v8bf*)(aB + 8192 + m * 1024);
#pragma unroll
    for (int n = 0; n < 4; ++n) b1[n] = *(const v8bf*)(bB + 8192 + n * 1024);
    WAIT_LGKM8;
    __builtin_amdgcn_s_setprio(1);
#pragma unroll
    for (int m = 0; m < 4; ++m)
#pragma unroll
      for (int n = 0; n < 4; ++n)
        acc[m][n] = __builtin_amdgcn_mfma_f32_16x16x32_bf16(a0[m], b0[n], acc[m][n], 0, 0, 0);
    __builtin_amdgcn_s_setprio(0); SCHEDB;
    WAIT_LGKM0;
    BARRIER;
    if (doStage) stage(buf);
    __builtin_amdgcn_s_setprio(1);
#pragma unroll
    for (int m = 0; m < 4; ++m)
#pragma unroll
      for (int n = 0; n < 4; ++n)
        acc[m][n] = __builtin_amdgcn_mfma_f32_16x16x32_bf16(a1[m], b1[n], acc[m][n], 0, 0, 0);
    __builtin_amdgcn_s_setprio(0); SCHEDB;
    gate();
    BARRIER;
  };

  stage(0);
  stage(1);
  WAIT_VM8;
  BARRIER; SCHEDB;

  const int NT = K >> 6;
  int t = 0;
  for (; t < NT - 2; ++t)
    tile(t & 1, true, [] { WAIT_VM8; });
  tile(t & 1, false, [] { WAIT_VM0; }); ++t;
  tile(t & 1, false, [] {});

  const int colb = n0 + wc * 64 + lr;
  const int rowb = m0 + wr * 64 + ls * 4;
#pragma unroll
  for (int n = 0; n < 4; ++n) {
    const int col = colb + n * 16;
    const float bv = bias[col];
    const bool rl = (col >= relu_from);
#pragma unroll
    for (int m = 0; m < 4; ++m) {
      const int rbase = rowb + m * 16;
#pragma unroll
      for (int j = 0; j < 4; ++j) {
        float v = acc[m][n][j] + bv;
        if (rl) v = fmaxf(v, 0.0f);
        C[(size_t)(rbase + j) * N + col] = __float2bfloat16(v);
      }
    }
  }
}

// ---------------------------------------------------------------------------
// G3 fused v7: round-4 GEMM core; seg-major packed masks + actions DMA'd
// coalesced into LDS at kernel start. LDS dests follow HW semantics:
// lane i lands at uniform_base + i*4 -> lo [0,256), hi [256,512), act [512,768).
// Epilogue: no-max softmax, LDS-broadcast masks, 9 cross-lane ops per row.
// ---------------------------------------------------------------------------

__global__ __launch_bounds__(256, 2)
void gemm_fused(const __hip_bfloat16* __restrict__ A,
                const __hip_bfloat16* __restrict__ Bt,
                const float* __restrict__ bias,
                const uint32_t* __restrict__ packedT,
                const int* __restrict__ actT,
                float2* __restrict__ partials,
                __hip_bfloat16* __restrict__ critic,
                int K) {
  __shared__ char smem[68608];

  const int tid  = threadIdx.x;
  const int lane = tid & 63;
  const int wave = tid >> 6;
  const int wr = wave >> 1, wc = wave & 1;
  const int lr = lane & 15, ls = lane >> 4;

  const int nwg = gridDim.x;
  const int q8 = nwg >> 3;
  const int id = (blockIdx.x & 7) * q8 + (blockIdx.x >> 3);
  const int bx = id % 24, by = id / 24;
  const int m0 = by * 128, n0 = bx * 128;

  const int seg = bx * 2 + wc;
  char* const mw = smem + 65536 + wave * 768;   // this wave's mask/act region

  // --- coalesced mask-bit + action DMA (oldest VMEM; hides under K-loop)
  // sources seg-major (lane stride 8B / 4B); dests per HW rule: base + lane*4
  if (bx < 20) {
    const int grow = m0 + wr * 64 + lane;
    const uint32_t* pm = packedT + ((size_t)(seg << 13) + grow) * 2;
    load_lds4(pm,     mw + lane * 4);          // lo -> [0,256)
    load_lds4(pm + 1, mw + 256 + lane * 4);    // hi -> [256,512)
    load_lds4(actT + (seg << 13) + grow, mw + 512 + lane * 4);  // act -> [512,768)
  }

  int r0, c0, r1, c1;
  decode_chunk(tid * 16, r0, c0);
  decode_chunk(tid * 16 + 4096, r1, c1);

  const size_t K2 = (size_t)K * 2;
  const char* pA0 = (const char*)A  + (size_t)(m0 + r0) * K2 + c0;
  const char* pA1 = (const char*)A  + (size_t)(m0 + r1) * K2 + c1;
  const char* pB0 = (const char*)Bt + (size_t)(n0 + r0) * K2 + c0;
  const char* pB1 = (const char*)Bt + (size_t)(n0 + r1) * K2 + c1;

  char* const s0 = smem + (tid << 4);

  auto stage = [&](int buf) {
    char* d = s0 + (buf << 15);
    load_lds16(pA0,      d);
    load_lds16(pA1,      d + 4096);
    load_lds16(pA0 + 64, d + 8192);
    load_lds16(pA1 + 64, d + 12288);
    load_lds16(pB0,      d + 16384);
    load_lds16(pB1,      d + 20480);
    load_lds16(pB0 + 64, d + 24576);
    load_lds16(pB1 + 64, d + 28672);
    pA0 += 128; pA1 += 128; pB0 += 128; pB1 += 128;
  };

  const int laneOff = lr * 64 + ((ls * 16) ^ ((lr & 8) << 2));

  v4f acc[4][4] = {};

  auto tile = [&](int buf, bool doStage, auto gate) {
    const char* aB = smem + (buf << 15) + wr * 4096 + laneOff;
    const char* bB = smem + (buf << 15) + 16384 + wc * 4096 + laneOff;
    v8bf a0[4], b0[4], a1[4], b1[4];
#pragma unroll
    for (int m = 0; m < 4; ++m) a0[m] = *(const v8bf*)(aB + m * 1024);
#pragma unroll
    for (int n = 0; n < 4; ++n) b0[n] = *(const v8bf*)(bB + n * 1024);
#pragma unroll
    for (int m = 0; m < 4; ++m) a1[m] = *(const v8bf*)(aB + 8192 + m * 1024);
#pragma unroll
    for (int n = 0; n < 4; ++n) b1[n] = *(const v8bf*)(bB + 8192 + n * 1024);
    WAIT_LGKM8;
    __builtin_amdgcn_s_setprio(1);
#pragma unroll
    for (int m = 0; m < 4; ++m)
#pragma unroll
      for (int n = 0; n < 4; ++n)
        acc[m][n] = __builtin_amdgcn_mfma_f32_16x16x32_bf16(a0[m], b0[n], acc[m][n], 0, 0, 0);
    __builtin_amdgcn_s_setprio(0); SCHEDB;
    WAIT_LGKM0;
    BARRIER;
    if (doStage) stage(buf);
    __builtin_amdgcn_s_setprio(1);
#pragma unroll
    for (int m = 0; m < 4; ++m)
#pragma unroll
      for (int n = 0; n < 4; ++n)
        acc[m][n] = __builtin_amdgcn_mfma_f32_16x16x32_bf16(a1[m], b1[n], acc[m][n], 0, 0, 0);
    __builtin_amdgcn_s_setprio(0); SCHEDB;
    gate();
    BARRIER;
  };

  stage(0);
  stage(1);
  WAIT_VM8;   // oldest (mask DMA + tile0) drain -> tile0 resident
  BARRIER; SCHEDB;

  const int NT = K >> 6;
  int t = 0;
  for (; t < NT - 2; ++t)
    tile(t & 1, true, [] { WAIT_VM8; });
  tile(t & 1, false, [] { WAIT_VM0; }); ++t;   // drains everything incl. masks
  tile(t & 1, false, [] {});

  const int rowb = m0 + wr * 64 + ls * 4;

  if (bx < 20) {
    float bv[4];
#pragma unroll
    for (int n = 0; n < 4; ++n) bv[n] = bias[n0 + wc * 64 + n * 16 + lr];

#pragma unroll
    for (int m = 0; m < 4; ++m) {
#pragma unroll
      for (int j = 0; j < 4; ++j) {
        const int lrow = ls * 4 + m * 16 + j;           // wave-local row 0..63
        const uint32_t lo = *(const uint32_t*)(mw + lrow * 4);
        const uint32_t hi = *(const uint32_t*)(mw + 256 + lrow * 4);
        const int act = *(const int*)(mw + 512 + lrow * 4);
        float v[4];
        v[0] = ((lo >> lr) & 1)        ? (acc[m][0][j] + bv[0]) : -1.0e9f;
        v[1] = ((lo >> (lr + 16)) & 1) ? (acc[m][1][j] + bv[1]) : -1.0e9f;
        v[2] = ((hi >> lr) & 1)        ? (acc[m][2][j] + bv[2]) : -1.0e9f;
        v[3] = ((hi >> (lr + 16)) & 1) ? (acc[m][3][j] + bv[3]) : -1.0e9f;
        // no-max softmax: logits O(1); exp(-1e9)=+0; 0*(-1e9)=0 (no NaN)
        float s = 0.f, sv = 0.f;
#pragma unroll
        for (int n = 0; n < 4; ++n) {
          const float e = __expf(v[n]);
          s += e; sv += e * v[n];
        }
#pragma unroll
        for (int o = 1; o < 16; o <<= 1) { s += __shfl_xor(s, o); sv += __shfl_xor(sv, o); }
        const float logZ = __logf(s);
        float va_loc = v[0];
        va_loc = (((act >> 4) & 3) == 1) ? v[1] : va_loc;
        va_loc = (((act >> 4) & 3) == 2) ? v[2] : va_loc;
        va_loc = (((act >> 4) & 3) == 3) ? v[3] : va_loc;
        const float va = __shfl(va_loc, (lane & 48) | (act & 15));
        float lp, ent;
        if ((unsigned)act < 64u) { lp = va - logZ; ent = logZ - sv / s; }
        else                     { lp = -1000.0f;  ent = 0.0f; }
        if (lr == 0) partials[(rowb + m * 16 + j) * 40 + seg] = make_float2(lp, ent);
      }
    }
  } else {
    // critic columns: relu + bf16 store to compact [8192][512]
    const int cb = (bx - 20) * 128 + wc * 64;
#pragma unroll
    for (int n = 0; n < 4; ++n) {
      const int col = cb + n * 16 + lr;
      const float bvv = bias[2560 + col];
#pragma unroll
      for (int m = 0; m < 4; ++m) {
        const int rbase = rowb + m * 16;
#pragma unroll
        for (int j = 0; j < 4; ++j)
          critic[(size_t)(rbase + j) * 512 + col] =
              __float2bfloat16(fmaxf(acc[m][n][j] + bvv, 0.0f));
      }
    }
  }
}

// ---------------------------------------------------------------------------
// finalize v3: tiny reduce — 40 f32 partial pairs + critic dot per row
// ---------------------------------------------------------------------------

__global__ __launch_bounds__(256)
void finalize3(const float2* __restrict__ partials,
               const __hip_bfloat16* __restrict__ critic,
               const float* __restrict__ Wc2,
               const float* __restrict__ bc2,
               float* __restrict__ out) {
  const int lane = threadIdx.x & 63;
  const int r = blockIdx.x * 4 + (threadIdx.x >> 6);

  float lp = 0.f, ent = 0.f;
  if (lane < 40) {
    const float2 t = partials[r * 40 + lane];
    lp = t.x; ent = t.y;
  }
#pragma unroll
  for (int o = 32; o > 0; o >>= 1) { lp += __shfl_xor(lp, o); ent += __shfl_xor(ent, o); }

  union { int4 q; __hip_bfloat16 h[8]; } c;
  c.q = *(const int4*)(critic + (size_t)r * 512 + lane * 8);
  const float4 w0 = *(const float4*)(Wc2 + lane * 8);
  const float4 w1 = *(const float4*)(Wc2 + lane * 8 + 4);
  float acc = __bfloat162float(c.h[0]) * w0.x + __bfloat162float(c.h[1]) * w0.y +
              __bfloat162float(c.h[2]) * w0.z + __bfloat162float(c.h[3]) * w0.w +
              __bfloat162float(c.h[4]) * w1.x + __bfloat162float(c.h[5]) * w1.y +
              __bfloat162float(c.h[6]) * w1.z + __bfloat162float(c.h[7]) * w1.w;
#pragma unroll
  for (int o = 32; o > 0; o >>= 1) acc += __shfl_xor(acc, o);

  if (lane == 0) {
    out[r]         = lp;
    out[8192 + r]  = ent;
    out[16384 + r] = acc + bc2[0];
  }
}

// ---------------------------------------------------------------------------

extern "C" void kernel_launch(void* const* d_in, const int* in_sizes, int n_in,
                              void* d_out, int out_size, void* d_ws, size_t ws_size,
                              hipStream_t stream) {
  const float* obs    = (const float*)d_in[0];
  const int*   actions= (const int*)d_in[1];
  const int*   masks  = (const int*)d_in[2];
  const float* W1     = (const float*)d_in[3];
  const float* b1     = (const float*)d_in[4];
  const float* W2     = (const float*)d_in[5];
  const float* b2     = (const float*)d_in[6];
  const float* headsW = (const float*)d_in[7];
  const float* headsb = (const float*)d_in[8];
  const float* Wc1    = (const float*)d_in[9];
  const float* bc1    = (const float*)d_in[10];
  const float* Wc2    = (const float*)d_in[11];
  const float* bc2    = (const float*)d_in[12];
  float* out = (float*)d_out;

  char* ws = (char*)d_ws;
  __hip_bfloat16* obsB  = (__hip_bfloat16*)(ws);              // 8192*512*2   = 8388608
  __hip_bfloat16* W1t   = (__hip_bfloat16*)(ws + 8388608);    // 1024*512*2   = 1048576
  __hip_bfloat16* W2t   = (__hip_bfloat16*)(ws + 9437184);    // 1024*1024*2  = 2097152
  __hip_bfloat16* Wbigt = (__hip_bfloat16*)(ws + 11534336);   // 3072*1024*2  = 6291456
  float*          biasc = (float*)(ws + 17825792);            // 3072*4       = 12288
  __hip_bfloat16* h1    = (__hip_bfloat16*)(ws + 17838080);   // 8192*1024*2  = 16777216
  __hip_bfloat16* h2    = (__hip_bfloat16*)(ws + 34615296);   // 8192*1024*2  = 16777216
  float2*      partials = (float2*)(ws + 51392512);           // 8192*40*8    = 2621440
  __hip_bfloat16* critic= (__hip_bfloat16*)(ws + 54013952);   // 8192*512*2   = 8388608
  uint32_t*    packedT  = (uint32_t*)(ws + 62402560);         // 40*8192*8    = 2621440
  int*         actT     = (int*)(ws + 65024000);              // 40*8192*4    = 1310720
  // total ws use: 66,334,720 bytes

  prep_kernel<<<7948, 256, 0, stream>>>(obs, W1, W2, headsW, Wc1, headsb, bc1,
                                        masks, actions, (int4*)obsB, W1t, W2t,
                                        Wbigt, biasc, packedT, actT);

  // G1/G2: 128x128 dbuf, 2 blocks/CU (512 blocks = 1 full CU-wave x2)
  gemm_db<<<dim3(512), 256, 0, stream>>>(obsB, W1t, b1, h1, 1024, 512, 0, 8);
  gemm_db<<<dim3(512), 256, 0, stream>>>(h1, W2t, b2, h2, 1024, 1024, 0, 8);

  // G3 fused: 24x64 = 1536 blocks (3 full CU-waves)
  gemm_fused<<<dim3(1536), 256, 0, stream>>>(h2, Wbigt, biasc, packedT, actT,
                                             partials, critic, 1024);

  finalize3<<<2048, 256, 0, stream>>>(partials, critic, Wc2, bc2, out);
}

// Round 14
// 131.737 us; speedup vs baseline: 1.1209x; 1.1209x over previous
//
#include <hip/hip_runtime.h>
#include <hip/hip_bf16.h>
#include <stdint.h>

// ---------------------------------------------------------------------------
// MaskedPolicy: obs->MLP->heads (masked log-softmax, gather, entropy) + critic
// B=8192 OBS=512 HID=1024 N*SUM=2560 (+512 critic cols = 3072 fused GEMM3)
// v13: G3 loads its raw mask rows into registers pre-K-loop (hidden), packs to
// bits in-register; epilogue transposes logits through wave-private LDS so
// each lane owns a full row -> pure-VALU softmax, ZERO cross-lane ops.
// ---------------------------------------------------------------------------

typedef __bf16 v8bf __attribute__((ext_vector_type(8)));
typedef float  v4f  __attribute__((ext_vector_type(4)));

__device__ __forceinline__ void load_lds16(const void* g, void* l) {
  auto gp = (const __attribute__((address_space(1))) char*)(uintptr_t)g;
  auto lp = (__attribute__((address_space(3))) char*)(uintptr_t)l;
  __builtin_amdgcn_global_load_lds(gp, lp, 16, 0, 0);
}

#define BARRIER __builtin_amdgcn_s_barrier()
#define SCHEDB  __builtin_amdgcn_sched_barrier(0)
#define WAIT_LGKM0 do { asm volatile("s_waitcnt lgkmcnt(0)" ::: "memory"); SCHEDB; } while (0)
#define WAIT_LGKM8 do { asm volatile("s_waitcnt lgkmcnt(8)" ::: "memory"); SCHEDB; } while (0)
#define WAIT_VM8   do { asm volatile("s_waitcnt vmcnt(8)" ::: "memory"); SCHEDB; } while (0)
#define WAIT_VM0   do { asm volatile("s_waitcnt vmcnt(0)" ::: "memory"); SCHEDB; } while (0)

// ---------------------------------------------------------------------------
// prep mega-kernel (R8-verified, no mask pass): transposes + obs + bias
// block ranges: [0,4608) transposes | [4608,6656) obs | [6656,6668) bias
// ---------------------------------------------------------------------------

__global__ __launch_bounds__(256)
void prep_kernel(const float* __restrict__ obs,
                 const float* __restrict__ W1, const float* __restrict__ W2,
                 const float* __restrict__ headsW, const float* __restrict__ Wc1,
                 const float* __restrict__ headsb, const float* __restrict__ bc1,
                 int4* __restrict__ obsB,
                 __hip_bfloat16* __restrict__ W1t, __hip_bfloat16* __restrict__ W2t,
                 __hip_bfloat16* __restrict__ Wbigt, float* __restrict__ biasc) {
  const int b = blockIdx.x;
  const int tid = threadIdx.x;
  if (b < 4608) {
    const float* in; __hip_bfloat16* outp; int R, C, bxx, byy;
    if (b < 512)       { in = W1;  outp = W1t; R = 512;  C = 1024; bxx = b % 32; byy = b / 32; }
    else if (b < 1536) { int i = b - 512;  in = W2;  outp = W2t; R = 1024; C = 1024; bxx = i % 32; byy = i / 32; }
    else if (b < 4096) { int i = b - 1536; int bz = i / 320; i %= 320;
                         in = headsW + (size_t)bz * 1024 * 320;
                         outp = Wbigt + (size_t)bz * 320 * 1024;
                         R = 1024; C = 320; bxx = i % 10; byy = i / 10; }
    else               { int i = b - 4096; in = Wc1; outp = Wbigt + 2560 * 1024;
                         R = 1024; C = 512; bxx = i % 16; byy = i / 16; }
    __shared__ float t[32][33];
    const int x = tid & 31, y = tid >> 5;
    const int bx0 = bxx * 32, by0 = byy * 32;
#pragma unroll
    for (int i = 0; i < 32; i += 8)
      t[y + i][x] = in[(size_t)(by0 + y + i) * C + bx0 + x];
    __syncthreads();
#pragma unroll
    for (int i = 0; i < 32; i += 8)
      outp[(size_t)(bx0 + y + i) * R + by0 + x] = __float2bfloat16(t[x][y + i]);
  } else if (b < 6656) {
    const int i = (b - 4608) * 256 + tid;   // < 524288
    const float4 x = ((const float4*)obs)[i * 2], y = ((const float4*)obs)[i * 2 + 1];
    union { __hip_bfloat16 h[8]; int4 v; } u;
    u.h[0] = __float2bfloat16(x.x); u.h[1] = __float2bfloat16(x.y);
    u.h[2] = __float2bfloat16(x.z); u.h[3] = __float2bfloat16(x.w);
    u.h[4] = __float2bfloat16(y.x); u.h[5] = __float2bfloat16(y.y);
    u.h[6] = __float2bfloat16(y.z); u.h[7] = __float2bfloat16(y.w);
    obsB[i] = u.v;
  } else {
    const int i = (b - 6656) * 256 + tid;
    if (i < 2560) biasc[i] = headsb[i];
    else if (i < 3072) biasc[i] = bc1[i - 2560];
  }
}

// ---------------------------------------------------------------------------
// shared swizzle helpers (verified: pass + 0 bank conflicts)
// ---------------------------------------------------------------------------

__device__ __forceinline__ void decode_chunk(int o, int& r, int& cb) {
  const int L = o ^ (((o >> 9) & 1) << 5);
  r  = ((L >> 10) << 4) | ((L >> 6) & 15);
  cb = ((L >> 4) & 3) << 4;
}

// ---------------------------------------------------------------------------
// G1/G2 GEMM: 128x128, BK=64, 4 waves, dbuf, 2 blocks/CU (round-4, verified)
// ---------------------------------------------------------------------------

__global__ __launch_bounds__(256, 2)
void gemm_db(const __hip_bfloat16* __restrict__ A,
             const __hip_bfloat16* __restrict__ Bt,
             const float* __restrict__ bias,
             __hip_bfloat16* __restrict__ C,
             int N, int K, int relu_from, int gx) {
  __shared__ char smem[65536];

  const int tid  = threadIdx.x;
  const int lane = tid & 63;
  const int wave = tid >> 6;
  const int wr = wave >> 1, wc = wave & 1;
  const int lr = lane & 15, ls = lane >> 4;

  const int nwg = gridDim.x;
  const int q8 = nwg >> 3;
  const int id = (blockIdx.x & 7) * q8 + (blockIdx.x >> 3);
  const int bx = id % gx, by = id / gx;
  const int m0 = by * 128, n0 = bx * 128;

  int r0, c0, r1, c1;
  decode_chunk(tid * 16, r0, c0);
  decode_chunk(tid * 16 + 4096, r1, c1);

  const size_t K2 = (size_t)K * 2;
  const char* pA0 = (const char*)A  + (size_t)(m0 + r0) * K2 + c0;
  const char* pA1 = (const char*)A  + (size_t)(m0 + r1) * K2 + c1;
  const char* pB0 = (const char*)Bt + (size_t)(n0 + r0) * K2 + c0;
  const char* pB1 = (const char*)Bt + (size_t)(n0 + r1) * K2 + c1;

  char* const s0 = smem + (tid << 4);

  auto stage = [&](int buf) {
    char* d = s0 + (buf << 15);
    load_lds16(pA0,      d);
    load_lds16(pA1,      d + 4096);
    load_lds16(pA0 + 64, d + 8192);
    load_lds16(pA1 + 64, d + 12288);
    load_lds16(pB0,      d + 16384);
    load_lds16(pB1,      d + 20480);
    load_lds16(pB0 + 64, d + 24576);
    load_lds16(pB1 + 64, d + 28672);
    pA0 += 128; pA1 += 128; pB0 += 128; pB1 += 128;
  };

  const int laneOff = lr * 64 + ((ls * 16) ^ ((lr & 8) << 2));

  v4f acc[4][4] = {};

  auto tile = [&](int buf, bool doStage, auto gate) {
    const char* aB = smem + (buf << 15) + wr * 4096 + laneOff;
    const char* bB = smem + (buf << 15) + 16384 + wc * 4096 + laneOff;
    v8bf a0[4], b0[4], a1[4], b1[4];
#pragma unroll
    for (int m = 0; m < 4; ++m) a0[m] = *(const v8bf*)(aB + m * 1024);
#pragma unroll
    for (int n = 0; n < 4; ++n) b0[n] = *(const v8bf*)(bB + n * 1024);
#pragma unroll
    for (int m = 0; m < 4; ++m) a1[m] = *(const v8bf*)(aB + 8192 + m * 1024);
#pragma unroll
    for (int n = 0; n < 4; ++n) b1[n] = *(const v8bf*)(bB + 8192 + n * 1024);
    WAIT_LGKM8;
    __builtin_amdgcn_s_setprio(1);
#pragma unroll
    for (int m = 0; m < 4; ++m)
#pragma unroll
      for (int n = 0; n < 4; ++n)
        acc[m][n] = __builtin_amdgcn_mfma_f32_16x16x32_bf16(a0[m], b0[n], acc[m][n], 0, 0, 0);
    __builtin_amdgcn_s_setprio(0); SCHEDB;
    WAIT_LGKM0;
    BARRIER;
    if (doStage) stage(buf);
    __builtin_amdgcn_s_setprio(1);
#pragma unroll
    for (int m = 0; m < 4; ++m)
#pragma unroll
      for (int n = 0; n < 4; ++n)
        acc[m][n] = __builtin_amdgcn_mfma_f32_16x16x32_bf16(a1[m], b1[n], acc[m][n], 0, 0, 0);
    __builtin_amdgcn_s_setprio(0); SCHEDB;
    gate();
    BARRIER;
  };

  stage(0);
  stage(1);
  WAIT_VM8;
  BARRIER; SCHEDB;

  const int NT = K >> 6;
  int t = 0;
  for (; t < NT - 2; ++t)
    tile(t & 1, true, [] { WAIT_VM8; });
  tile(t & 1, false, [] { WAIT_VM0; }); ++t;
  tile(t & 1, false, [] {});

  const int colb = n0 + wc * 64 + lr;
  const int rowb = m0 + wr * 64 + ls * 4;
#pragma unroll
  for (int n = 0; n < 4; ++n) {
    const int col = colb + n * 16;
    const float bv = bias[col];
    const bool rl = (col >= relu_from);
#pragma unroll
    for (int m = 0; m < 4; ++m) {
      const int rbase = rowb + m * 16;
#pragma unroll
      for (int j = 0; j < 4; ++j) {
        float v = acc[m][n][j] + bv;
        if (rl) v = fmaxf(v, 0.0f);
        C[(size_t)(rbase + j) * N + col] = __float2bfloat16(v);
      }
    }
  }
}

// ---------------------------------------------------------------------------
// G3 fused v8: GEMM core; each policy lane loads ITS row's raw masks (16xint4,
// dense) + action pre-K-loop (hidden), packs to 2 bit-words post-prologue.
// Epilogue: logits+bias -> wave-private LDS [64][68] bf16 transpose; lane l
// re-reads row l and does a pure-VALU no-max softmax (no shfl, no barrier).
// Partials stored seg-major (coalesced).
// ---------------------------------------------------------------------------

__global__ __launch_bounds__(256, 2)
void gemm_fused(const __hip_bfloat16* __restrict__ A,
                const __hip_bfloat16* __restrict__ Bt,
                const float* __restrict__ bias,
                const int* __restrict__ masks,
                const int* __restrict__ actions,
                float2* __restrict__ partialsT,
                __hip_bfloat16* __restrict__ critic,
                int K) {
  __shared__ char smem[65536];

  const int tid  = threadIdx.x;
  const int lane = tid & 63;
  const int wave = tid >> 6;
  const int wr = wave >> 1, wc = wave & 1;
  const int lr = lane & 15, ls = lane >> 4;

  const int nwg = gridDim.x;
  const int q8 = nwg >> 3;
  const int id = (blockIdx.x & 7) * q8 + (blockIdx.x >> 3);
  const int bx = id % 24, by = id / 24;
  const int m0 = by * 128, n0 = bx * 128;

  const int seg = bx * 2 + wc;
  const int myrow = m0 + wr * 64 + lane;   // this lane's output row

  // --- issue this lane's mask row (256B dense) + action FIRST (oldest VMEM;
  //     completes under the K-loop; drained by the prologue vmcnt gate)
  int4 mk[16];
  int actv = 0;
  if (bx < 20) {
    const int4* mp = (const int4*)(masks + (size_t)myrow * 2560 + seg * 64);
#pragma unroll
    for (int q = 0; q < 16; ++q) mk[q] = mp[q];
    actv = actions[myrow * 40 + seg];
  }
  SCHEDB;   // pin: mask loads issue before staging

  int r0, c0, r1, c1;
  decode_chunk(tid * 16, r0, c0);
  decode_chunk(tid * 16 + 4096, r1, c1);

  const size_t K2 = (size_t)K * 2;
  const char* pA0 = (const char*)A  + (size_t)(m0 + r0) * K2 + c0;
  const char* pA1 = (const char*)A  + (size_t)(m0 + r1) * K2 + c1;
  const char* pB0 = (const char*)Bt + (size_t)(n0 + r0) * K2 + c0;
  const char* pB1 = (const char*)Bt + (size_t)(n0 + r1) * K2 + c1;

  char* const s0 = smem + (tid << 4);

  auto stage = [&](int buf) {
    char* d = s0 + (buf << 15);
    load_lds16(pA0,      d);
    load_lds16(pA1,      d + 4096);
    load_lds16(pA0 + 64, d + 8192);
    load_lds16(pA1 + 64, d + 12288);
    load_lds16(pB0,      d + 16384);
    load_lds16(pB1,      d + 20480);
    load_lds16(pB0 + 64, d + 24576);
    load_lds16(pB1 + 64, d + 28672);
    pA0 += 128; pA1 += 128; pB0 += 128; pB1 += 128;
  };

  const int laneOff = lr * 64 + ((ls * 16) ^ ((lr & 8) << 2));

  v4f acc[4][4] = {};

  auto tile = [&](int buf, bool doStage, auto gate) {
    const char* aB = smem + (buf << 15) + wr * 4096 + laneOff;
    const char* bB = smem + (buf << 15) + 16384 + wc * 4096 + laneOff;
    v8bf a0[4], b0[4], a1[4], b1[4];
#pragma unroll
    for (int m = 0; m < 4; ++m) a0[m] = *(const v8bf*)(aB + m * 1024);
#pragma unroll
    for (int n = 0; n < 4; ++n) b0[n] = *(const v8bf*)(bB + n * 1024);
#pragma unroll
    for (int m = 0; m < 4; ++m) a1[m] = *(const v8bf*)(aB + 8192 + m * 1024);
#pragma unroll
    for (int n = 0; n < 4; ++n) b1[n] = *(const v8bf*)(bB + 8192 + n * 1024);
    WAIT_LGKM8;
    __builtin_amdgcn_s_setprio(1);
#pragma unroll
    for (int m = 0; m < 4; ++m)
#pragma unroll
      for (int n = 0; n < 4; ++n)
        acc[m][n] = __builtin_amdgcn_mfma_f32_16x16x32_bf16(a0[m], b0[n], acc[m][n], 0, 0, 0);
    __builtin_amdgcn_s_setprio(0); SCHEDB;
    WAIT_LGKM0;
    BARRIER;
    if (doStage) stage(buf);
    __builtin_amdgcn_s_setprio(1);
#pragma unroll
    for (int m = 0; m < 4; ++m)
#pragma unroll
      for (int n = 0; n < 4; ++n)
        acc[m][n] = __builtin_amdgcn_mfma_f32_16x16x32_bf16(a1[m], b1[n], acc[m][n], 0, 0, 0);
    __builtin_amdgcn_s_setprio(0); SCHEDB;
    gate();
    BARRIER;
  };

  stage(0);
  stage(1);
  WAIT_VM8;   // drains masks (oldest) + tile0
  BARRIER; SCHEDB;

  // pack mask ints -> 2 bit-words (frees the 64 mask VGPRs for the K-loop)
  uint32_t lo = 0, hi = 0;
  if (bx < 20) {
#pragma unroll
    for (int q = 0; q < 8; ++q) {
      lo |= (mk[q].x ? 1u : 0u) << (4 * q);
      lo |= (mk[q].y ? 1u : 0u) << (4 * q + 1);
      lo |= (mk[q].z ? 1u : 0u) << (4 * q + 2);
      lo |= (mk[q].w ? 1u : 0u) << (4 * q + 3);
    }
#pragma unroll
    for (int q = 0; q < 8; ++q) {
      hi |= (mk[8 + q].x ? 1u : 0u) << (4 * q);
      hi |= (mk[8 + q].y ? 1u : 0u) << (4 * q + 1);
      hi |= (mk[8 + q].z ? 1u : 0u) << (4 * q + 2);
      hi |= (mk[8 + q].w ? 1u : 0u) << (4 * q + 3);
    }
  }
  SCHEDB;

  const int NT = K >> 6;
  int t = 0;
  for (; t < NT - 2; ++t)
    tile(t & 1, true, [] { WAIT_VM8; });
  tile(t & 1, false, [] { WAIT_VM0; }); ++t;
  tile(t & 1, false, [] {});
  // final BARRIER above -> all waves done with dbufs; LDS reusable

  const int rowb = m0 + wr * 64 + ls * 4;

  if (bx < 20) {
    float bv[4];
#pragma unroll
    for (int n = 0; n < 4; ++n) bv[n] = bias[n0 + wc * 64 + n * 16 + lr];

    // transpose logits through wave-private LDS [64][68] bf16 (8704B/wave)
    char* const wl = smem + wave * 8704;
#pragma unroll
    for (int m = 0; m < 4; ++m)
#pragma unroll
      for (int n = 0; n < 4; ++n)
#pragma unroll
        for (int j = 0; j < 4; ++j) {
          const int lrow = m * 16 + ls * 4 + j;
          *(__hip_bfloat16*)(wl + lrow * 136 + (n * 16 + lr) * 2) =
              __float2bfloat16(acc[m][n][j] + bv[n]);
        }
    WAIT_LGKM0;   // wave-private: no barrier needed

    // lane processes its own full row: pure VALU, no cross-lane
    const char* rb = wl + lane * 136;
    float s = 0.f, sv = 0.f, va = 0.f;
#pragma unroll
    for (int k = 0; k < 16; ++k) {
      const ushort4 w = *(const ushort4*)(rb + k * 8);
#pragma unroll
      for (int c4 = 0; c4 < 4; ++c4) {
        const int c = k * 4 + c4;
        const uint16_t us = (c4 == 0) ? w.x : (c4 == 1) ? w.y : (c4 == 2) ? w.z : w.w;
        union { uint32_t u; float f; } cv; cv.u = (uint32_t)us << 16;
        const uint32_t half = (c < 32) ? lo : hi;   // compile-time select
        const float v = ((half >> (c & 31)) & 1) ? cv.f : -1.0e9f;
        const float e = __expf(v);   // no-max softmax: logits O(1), exp(-1e9)=0
        s += e;
        sv = fmaf(v, e, sv);
        va = (actv == c) ? v : va;
      }
    }
    const float logZ = __logf(s);
    float lp, ent;
    if ((unsigned)actv < 64u) { lp = va - logZ; ent = logZ - sv / s; }
    else                      { lp = -1000.0f;  ent = 0.0f; }
    partialsT[(seg << 13) + myrow] = make_float2(lp, ent);   // coalesced
  } else {
    // critic columns: relu + bf16 store to compact [8192][512]
    const int cb = (bx - 20) * 128 + wc * 64;
#pragma unroll
    for (int n = 0; n < 4; ++n) {
      const int col = cb + n * 16 + lr;
      const float bvv = bias[2560 + col];
#pragma unroll
      for (int m = 0; m < 4; ++m) {
        const int rbase = rowb + m * 16;
#pragma unroll
        for (int j = 0; j < 4; ++j)
          critic[(size_t)(rbase + j) * 512 + col] =
              __float2bfloat16(fmaxf(acc[m][n][j] + bvv, 0.0f));
      }
    }
  }
}

// ---------------------------------------------------------------------------
// finalize v4: reduce 40 seg-major partial pairs + critic dot per row
// ---------------------------------------------------------------------------

__global__ __launch_bounds__(256)
void finalize3(const float2* __restrict__ partialsT,
               const __hip_bfloat16* __restrict__ critic,
               const float* __restrict__ Wc2,
               const float* __restrict__ bc2,
               float* __restrict__ out) {
  const int lane = threadIdx.x & 63;
  const int r = blockIdx.x * 4 + (threadIdx.x >> 6);

  float lp = 0.f, ent = 0.f;
  if (lane < 40) {
    const float2 t = partialsT[(lane << 13) + r];
    lp = t.x; ent = t.y;
  }
#pragma unroll
  for (int o = 32; o > 0; o >>= 1) { lp += __shfl_xor(lp, o); ent += __shfl_xor(ent, o); }

  union { int4 q; __hip_bfloat16 h[8]; } c;
  c.q = *(const int4*)(critic + (size_t)r * 512 + lane * 8);
  const float4 w0 = *(const float4*)(Wc2 + lane * 8);
  const float4 w1 = *(const float4*)(Wc2 + lane * 8 + 4);
  float acc = __bfloat162float(c.h[0]) * w0.x + __bfloat162float(c.h[1]) * w0.y +
              __bfloat162float(c.h[2]) * w0.z + __bfloat162float(c.h[3]) * w0.w +
              __bfloat162float(c.h[4]) * w1.x + __bfloat162float(c.h[5]) * w1.y +
              __bfloat162float(c.h[6]) * w1.z + __bfloat162float(c.h[7]) * w1.w;
#pragma unroll
  for (int o = 32; o > 0; o >>= 1) acc += __shfl_xor(acc, o);

  if (lane == 0) {
    out[r]         = lp;
    out[8192 + r]  = ent;
    out[16384 + r] = acc + bc2[0];
  }
}

// ---------------------------------------------------------------------------

extern "C" void kernel_launch(void* const* d_in, const int* in_sizes, int n_in,
                              void* d_out, int out_size, void* d_ws, size_t ws_size,
                              hipStream_t stream) {
  const float* obs    = (const float*)d_in[0];
  const int*   actions= (const int*)d_in[1];
  const int*   masks  = (const int*)d_in[2];
  const float* W1     = (const float*)d_in[3];
  const float* b1     = (const float*)d_in[4];
  const float* W2     = (const float*)d_in[5];
  const float* b2     = (const float*)d_in[6];
  const float* headsW = (const float*)d_in[7];
  const float* headsb = (const float*)d_in[8];
  const float* Wc1    = (const float*)d_in[9];
  const float* bc1    = (const float*)d_in[10];
  const float* Wc2    = (const float*)d_in[11];
  const float* bc2    = (const float*)d_in[12];
  float* out = (float*)d_out;

  char* ws = (char*)d_ws;
  __hip_bfloat16* obsB  = (__hip_bfloat16*)(ws);              // 8192*512*2   = 8388608
  __hip_bfloat16* W1t   = (__hip_bfloat16*)(ws + 8388608);    // 1024*512*2   = 1048576
  __hip_bfloat16* W2t   = (__hip_bfloat16*)(ws + 9437184);    // 1024*1024*2  = 2097152
  __hip_bfloat16* Wbigt = (__hip_bfloat16*)(ws + 11534336);   // 3072*1024*2  = 6291456
  float*          biasc = (float*)(ws + 17825792);            // 3072*4       = 12288
  __hip_bfloat16* h1    = (__hip_bfloat16*)(ws + 17838080);   // 8192*1024*2  = 16777216
  __hip_bfloat16* h2    = (__hip_bfloat16*)(ws + 34615296);   // 8192*1024*2  = 16777216
  float2*     partialsT = (float2*)(ws + 51392512);           // 40*8192*8    = 2621440
  __hip_bfloat16* critic= (__hip_bfloat16*)(ws + 54013952);   // 8192*512*2   = 8388608
  // total ws use: 62,402,560 bytes

  prep_kernel<<<6668, 256, 0, stream>>>(obs, W1, W2, headsW, Wc1, headsb, bc1,
                                        (int4*)obsB, W1t, W2t, Wbigt, biasc);

  // G1/G2: 128x128 dbuf, 2 blocks/CU (512 blocks = 1 full CU-wave x2)
  gemm_db<<<dim3(512), 256, 0, stream>>>(obsB, W1t, b1, h1, 1024, 512, 0, 8);
  gemm_db<<<dim3(512), 256, 0, stream>>>(h1, W2t, b2, h2, 1024, 1024, 0, 8);

  // G3 fused: 24x64 = 1536 blocks (3 full CU-waves)
  gemm_fused<<<dim3(1536), 256, 0, stream>>>(h2, Wbigt, biasc, masks, actions,
                                             partialsT, critic, 1024);

  finalize3<<<2048, 256, 0, stream>>>(partialsT, critic, Wc2, bc2, out);
}